// Round 5
// baseline (358.290 us; speedup 1.0000x reference)
//
#include <hip/hip_runtime.h>
#include <hip/hip_bf16.h>
#include <math.h>

// Problem constants (fixed by reference)
#define NN 100000   // nodes
#define FF 128      // features
#define DD 16       // degree
#define KK 8        // hashers
#define HH 256      // hash dim
#define OO 256      // out dim
#define KH 2048     // K*H
#define TASKS 6250  // 100000 / 16 rows per task (exact)
#define BPAD 280    // LDS B row stride in shorts: 560 B = 35x16 (aligned), 140 dw % 32 = 12 -> 2-way banks (free)

// out[n,o] = ELU( sum_f nm[n,f]*An[f,o] + sum_f x[n,f]*As[f,o] + bias[o] )
// An = R_flat @ Wn^T, As = R_flat @ Ws^T  (256x256 collapsed weight, bf16)
// R5: gather source in fp8 e4m3 (rows 128 B -> half the random-read bytes AND half the
// 64-B line requests vs bf16; both R2 and R4 gathers plateaued at ~2.2 TB/s on the
// L2-miss path). 1024-thr fused blocks (16 waves/CU vs 8). cast merged into wgemm dispatch.

using frag_t  = __attribute__((ext_vector_type(8))) short;   // 8 bf16 = 4 VGPR (MFMA A/B frag)
using f32x4   = __attribute__((ext_vector_type(4))) float;   // MFMA C/D frag
using ushort8 = __attribute__((ext_vector_type(8))) unsigned short;
using v2f     = __attribute__((ext_vector_type(2))) float;

static __device__ __forceinline__ float u2f(unsigned int u) {
    union { unsigned int i; float f; } v; v.i = u; return v.f;
}
static __device__ __forceinline__ unsigned short f2bf(float f) {
    union { float f; unsigned int i; } v; v.f = f;
    unsigned int x = v.i;
    x += 0x7fffu + ((x >> 16) & 1u);   // round-to-nearest-even
    return (unsigned short)(x >> 16);
}

// ------- Kernel 1: merged prep: blocks 0..127 = weight GEMM, blocks 128.. = x cast -------
// wgemm: P[z][f2][o] = sum_{j in z-chunk} R_flat[f2&127,j] * W[o,j]; bx -> (x,y,z)=(bx&3,(bx>>2)&3,bx>>4)
// cast: x fp32 -> xb bf16 (for self-frags) and xb8 fp8-e4m3 (for the neighbor gather)
__global__ __launch_bounds__(256) void k_prep(const float* __restrict__ x,
                                              const float* __restrict__ R,
                                              const float* __restrict__ Ws,
                                              const float* __restrict__ Wn,
                                              float* __restrict__ P,
                                              unsigned short* __restrict__ xb,
                                              unsigned int* __restrict__ xb8) {
    __shared__ float a_s[16][68];
    __shared__ float w_s[16][68];
    int t = threadIdx.x;
    if (blockIdx.x >= 128) {
        // ---- cast part: 6250 blocks, 8 floats/thread ----
        int g = (blockIdx.x - 128) * 256 + t;
        const float4* xv = (const float4*)x;
        float4 a = xv[2 * g], b = xv[2 * g + 1];
        ushort8 o;
        o[0] = f2bf(a.x); o[1] = f2bf(a.y); o[2] = f2bf(a.z); o[3] = f2bf(a.w);
        o[4] = f2bf(b.x); o[5] = f2bf(b.y); o[6] = f2bf(b.z); o[7] = f2bf(b.w);
        *(ushort8*)(xb + (size_t)g * 8) = o;
        int lo = __builtin_amdgcn_cvt_pk_fp8_f32(a.x, a.y, 0, false);
        lo     = __builtin_amdgcn_cvt_pk_fp8_f32(a.z, a.w, lo, true);
        int hi = __builtin_amdgcn_cvt_pk_fp8_f32(b.x, b.y, 0, false);
        hi     = __builtin_amdgcn_cvt_pk_fp8_f32(b.z, b.w, hi, true);
        uint2 o8; o8.x = (unsigned int)lo; o8.y = (unsigned int)hi;
        *(uint2*)(xb8 + (size_t)g * 2) = o8;
        return;
    }
    // ---- wgemm part: 128 blocks ----
    int bx = blockIdx.x & 3, by = (blockIdx.x >> 2) & 3, bz = blockIdx.x >> 4;
    const float* W = (bx < 2) ? Wn : Ws;          // f2 0..127 -> Wn (neigh), else Ws (self)
    int fbase = (bx & 1) * 64;
    int tx = t & 15, ty = t >> 4;
    int lf = t >> 2;              // 0..63: ff (R row) / oo (W row)
    int j4 = (t & 3) * 4;         // 0,4,8,12
    float acc[4][4] = {};
    const float* Rb = R + (size_t)bz * (FF * HH) + (size_t)(fbase + lf) * HH;
    const float* Wb = W + (size_t)(by * 64 + lf) * KH + (size_t)bz * 256;
    for (int ks = 0; ks < 16; ++ks) {
        float4 av = *(const float4*)(Rb + ks * 16 + j4);
        float4 wv = *(const float4*)(Wb + ks * 16 + j4);
        __syncthreads();
        a_s[j4 + 0][lf] = av.x; a_s[j4 + 1][lf] = av.y;
        a_s[j4 + 2][lf] = av.z; a_s[j4 + 3][lf] = av.w;
        w_s[j4 + 0][lf] = wv.x; w_s[j4 + 1][lf] = wv.y;
        w_s[j4 + 2][lf] = wv.z; w_s[j4 + 3][lf] = wv.w;
        __syncthreads();
#pragma unroll
        for (int jj = 0; jj < 16; ++jj) {
            float ar[4], wr[4];
#pragma unroll
            for (int i = 0; i < 4; ++i) ar[i] = a_s[jj][ty * 4 + i];
#pragma unroll
            for (int j = 0; j < 4; ++j) wr[j] = w_s[jj][tx * 4 + j];
#pragma unroll
            for (int i = 0; i < 4; ++i)
#pragma unroll
                for (int j = 0; j < 4; ++j) acc[i][j] += ar[i] * wr[j];
        }
    }
    float* Pb = P + (size_t)bz * 65536 + (size_t)(bx * 64) * 256 + by * 64;
#pragma unroll
    for (int i = 0; i < 4; ++i) {
        float4 v = make_float4(acc[i][0], acc[i][1], acc[i][2], acc[i][3]);
        *(float4*)(Pb + (size_t)(ty * 4 + i) * 256 + tx * 4) = v;
    }
}

// ---- Kernel 2: combine 8 partials, transpose to Bbf[o][f2] (bf16); zero task counter ----
__global__ __launch_bounds__(256) void k_comb(const float* __restrict__ P,
                                              unsigned short* __restrict__ Bbf,
                                              unsigned int* __restrict__ counter) {
    __shared__ float tsh[64][65];
    int bf = blockIdx.x, bo = blockIdx.y;    // 4x4 tiles of 64
    int t = threadIdx.x;
    if (bf == 0 && bo == 0 && t == 0) *counter = 0u;   // stream-ordered init for k_fused
    for (int e = t; e < 4096; e += 256) {
        int r = e >> 6, c = e & 63;
        float s = 0.f;
#pragma unroll
        for (int z = 0; z < 8; ++z)
            s += P[(size_t)z * 65536 + (size_t)(bf * 64 + r) * 256 + bo * 64 + c];
        tsh[r][c] = s;
    }
    __syncthreads();
    for (int e = t; e < 4096; e += 256) {
        int r = e >> 6, c = e & 63;
        Bbf[(size_t)(bo * 64 + r) * 256 + bf * 64 + c] = f2bf(tsh[c][r]);
    }
}

// ---------------- Kernel 3: fused gather-mean + MFMA GEMM + bias + ELU ----------------
// Block: 1024 thr (16 waves), grid 256, 1 block/CU (LDS 144 KB). Barrier-free main loop.
// Wave task = 16 output rows. A-frag: lane(l15,quad) holds A[m0+l15][f*32+quad*8 ..+7];
// k 0..127 = neigh mean (fp8 gather, fp32 acc -> bf16), k 128..255 = self feats (bf16).
// B[o][k] LDS-resident. C/D: col=l15, row=quad*4+reg.
__global__ __launch_bounds__(1024) void k_fused(const unsigned short* __restrict__ xb,
                                                const unsigned char* __restrict__ xb8,
                                                const int* __restrict__ nbr,
                                                const unsigned short* __restrict__ Bbf,
                                                const float* __restrict__ bias,
                                                float* __restrict__ C,
                                                unsigned int* __restrict__ counter) {
    extern __shared__ unsigned short Bls[];                    // [256][BPAD] shorts, then bias fp32[256]
    float* bias_ls = (float*)(Bls + 256 * BPAD);
    int t = threadIdx.x;
    // stage B: 256 rows x 32 chunks of 8 shorts = 8192 chunks, 8/thread
#pragma unroll
    for (int i = 0; i < 8; ++i) {
        int id = t + i * 1024;
        int row = id >> 5, cc = id & 31;
        *(ushort8*)(Bls + row * BPAD + cc * 8) = *(const ushort8*)(Bbf + row * 256 + cc * 8);
    }
    if (t < 256) bias_ls[t] = bias[t];
    __syncthreads();

    int lane = t & 63;
    int l15 = lane & 15, quad = lane >> 4;

    for (;;) {
        unsigned int task;
        if (lane == 0) task = atomicAdd(counter, 1u);
        task = __builtin_amdgcn_readfirstlane(task);
        if (task >= TASKS) break;
        int m0 = (int)task * 16;
        int row = m0 + l15;

        // neighbor indices for this lane's row (redundant across quads; L2-cached)
        const int4* nb = (const int4*)(nbr + (size_t)row * 16);
        int4 i0 = nb[0], i1 = nb[1], i2 = nb[2], i3 = nb[3];
        int idxv[16] = { i0.x, i0.y, i0.z, i0.w, i1.x, i1.y, i1.z, i1.w,
                         i2.x, i2.y, i2.z, i2.w, i3.x, i3.y, i3.z, i3.w };

        f32x4 acc[16] = {};

        // ---- neigh half: k-frags f=0..3 (features f*32 + quad*8, fp8 rows of 128 B) ----
#pragma unroll
        for (int f = 0; f < 4; ++f) {
            float s[8] = {0.f, 0.f, 0.f, 0.f, 0.f, 0.f, 0.f, 0.f};
            const unsigned char* basep = xb8 + f * 32 + quad * 8;
#pragma unroll
            for (int h = 0; h < 2; ++h) {        // two batches of 8 in-flight 8-B loads
                uint2 wb[8];
#pragma unroll
                for (int d = 0; d < 8; ++d)
                    wb[d] = *(const uint2*)(basep + (size_t)idxv[h * 8 + d] * 128);
#pragma unroll
                for (int d = 0; d < 8; ++d) {
                    v2f p0 = __builtin_amdgcn_cvt_pk_f32_fp8((int)wb[d].x, false);
                    v2f p1 = __builtin_amdgcn_cvt_pk_f32_fp8((int)wb[d].x, true);
                    v2f p2 = __builtin_amdgcn_cvt_pk_f32_fp8((int)wb[d].y, false);
                    v2f p3 = __builtin_amdgcn_cvt_pk_f32_fp8((int)wb[d].y, true);
                    s[0] += p0.x; s[1] += p0.y; s[2] += p1.x; s[3] += p1.y;
                    s[4] += p2.x; s[5] += p2.y; s[6] += p3.x; s[7] += p3.y;
                }
            }
            frag_t af;
#pragma unroll
            for (int j = 0; j < 8; ++j) af[j] = (short)f2bf(s[j] * 0.0625f);
#pragma unroll
            for (int j = 0; j < 16; ++j) {
                frag_t bfr = *(const frag_t*)(Bls + (j * 16 + l15) * BPAD + f * 32 + quad * 8);
                acc[j] = __builtin_amdgcn_mfma_f32_16x16x32_bf16(af, bfr, acc[j], 0, 0, 0);
            }
        }
        // ---- self half: k-frags f=4..7 from bf16 xb (features (f-4)*32 + quad*8) ----
#pragma unroll
        for (int f = 4; f < 8; ++f) {
            frag_t af = *(const frag_t*)(xb + (size_t)row * 128 + (f - 4) * 32 + quad * 8);
#pragma unroll
            for (int j = 0; j < 16; ++j) {
                frag_t bfr = *(const frag_t*)(Bls + (j * 16 + l15) * BPAD + f * 32 + quad * 8);
                acc[j] = __builtin_amdgcn_mfma_f32_16x16x32_bf16(af, bfr, acc[j], 0, 0, 0);
            }
        }
        // ---- epilogue: bias + ELU, fp32 store ----
        int r0 = m0 + quad * 4;
#pragma unroll
        for (int j = 0; j < 16; ++j) {
            int col = j * 16 + l15;
            float bv = bias_ls[col];
#pragma unroll
            for (int r = 0; r < 4; ++r) {
                float v = acc[j][r] + bv;
                C[(size_t)(r0 + r) * 256 + col] = (v > 0.f) ? v : expm1f(v);
            }
        }
    }
}

// ---------------------------------- launcher ----------------------------------
extern "C" void kernel_launch(void* const* d_in, const int* in_sizes, int n_in,
                              void* d_out, int out_size, void* d_ws, size_t ws_size,
                              hipStream_t stream) {
    const float* x    = (const float*)d_in[0];
    const int*   nbr  = (const int*)d_in[1];
    const float* R    = (const float*)d_in[2];
    const float* Ws   = (const float*)d_in[3];
    const float* Wn   = (const float*)d_in[4];
    const float* bias = (const float*)d_in[5];
    float* out = (float*)d_out;

    // workspace (16B-aligned): xb 25.6MB | xb8 12.8MB | P 2MB | Bbf 128KB | counter
    char* ws = (char*)d_ws;
    unsigned short* xb  = (unsigned short*)(ws);
    unsigned int*   xb8 = (unsigned int*)(ws + 25600000);
    float*          P   = (float*)(ws + 25600000 + 12800000);
    unsigned short* Bbf = (unsigned short*)(ws + 25600000 + 12800000 + 2097152);
    unsigned int*   cnt = (unsigned int*)(ws + 25600000 + 12800000 + 2097152 + 131072);

    const int lds_bytes = 256 * BPAD * 2 + 256 * 4;   // 143360 + 1024 = 144384 B
    hipFuncSetAttribute((const void*)k_fused,
                        hipFuncAttributeMaxDynamicSharedMemorySize, lds_bytes);

    hipLaunchKernelGGL(k_prep, dim3(128 + 6250), dim3(256), 0, stream,
                       x, R, Ws, Wn, P, xb, xb8);
    hipLaunchKernelGGL(k_comb, dim3(4, 4), dim3(256), 0, stream, P, Bbf, cnt);
    hipLaunchKernelGGL(k_fused, dim3(256), dim3(1024), lds_bytes, stream,
                       xb, (const unsigned char*)xb8, nbr, Bbf, bias, out, cnt);
}